// Round 5
// baseline (42.035 us; speedup 1.0000x reference)
//
#include <hip/hip_runtime.h>

#define POOL 7
#define NPTS 49
#define NBUCKET 256
#define NB_CONV 2048

typedef float    f4 __attribute__((ext_vector_type(4)));
typedef _Float16 h4 __attribute__((ext_vector_type(4)));

__device__ __forceinline__ f4 ld4f(const float* p) { return *(const f4*)p; }

__device__ __forceinline__ int roi_level(float dy, float dx) {
    // matches jnp: log2(sqrt(max(h*w,0)) / 0.21875 + 1e-8), round half-even
    const float rl = log2f(sqrtf(fmaxf(dy * dx, 0.0f)) / 0.21875f + 1e-8f);
    int lvl = 4 + (int)rintf(rl);
    return lvl < 3 ? 3 : (lvl > 6 ? 6 : lvl);
}

// Fused prepass: blocks [0, NB_CONV) convert p3|p4 f32 -> f16 into ws;
// block NB_CONV counting-sorts ROIs by (batch, level, y/64) -> order[].
__global__ __launch_bounds__(256) void prepass_kernel(
    const float* __restrict__ p3, const float* __restrict__ p4,
    _Float16* __restrict__ hmem, int n3_4, int ntot_4,
    const float* __restrict__ props, int* __restrict__ order, int BN, int N)
{
    const int bid = blockIdx.x;
    if (bid < NB_CONV) {
        const int tid0 = bid * 256 + threadIdx.x;
        for (int i = tid0; i < ntot_4; i += NB_CONV * 256) {
            const float* src = i < n3_4 ? p3 + (size_t)i * 4
                                        : p4 + ((size_t)(i - n3_4)) * 4;
            const f4 v = ld4f(src);
            h4 h;
            h.x = (_Float16)v.x; h.y = (_Float16)v.y;
            h.z = (_Float16)v.z; h.w = (_Float16)v.w;
            *(h4*)(hmem + (size_t)i * 4) = h;
        }
        return;
    }

    // ---- sort block ----
    __shared__ unsigned char keys[2048];
    __shared__ int hist[NBUCKET];
    __shared__ int offs[NBUCKET];
    const int tid = threadIdx.x;
    if (tid < NBUCKET) hist[tid] = 0;
    __syncthreads();
    for (int r = tid; r < BN; r += 256) {
        const f4 p = ld4f(props + (size_t)r * 4);
        const int lvl = roi_level(p.z - p.x, p.w - p.y);
        int lg = lvl - 3; lg = lg < 0 ? 0 : (lg > 1 ? 1 : lg);  // data hits {3,4}
        const float yc = 0.5f * (p.x + p.z);
        int yq = (int)(yc * 64.0f);
        yq = yq < 0 ? 0 : (yq > 63 ? 63 : yq);
        const int b = r >= N ? 1 : 0;
        const int k = (b << 7) | (lg << 6) | yq;
        keys[r] = (unsigned char)k;
        atomicAdd(&hist[k], 1);
    }
    __syncthreads();
    if (tid == 0) {
        int acc = 0;
        for (int i = 0; i < NBUCKET; ++i) { offs[i] = acc; acc += hist[i]; }
    }
    __syncthreads();
    for (int r = tid; r < BN; r += 256) {
        const int pos = atomicAdd(&offs[keys[r]], 1);
        order[pos] = r;
    }
}

// Main: one block per sorted ROI slot, 4 waves = 4 point-lanes, each wave's
// 64 lanes cover all 256 channels (4 ch/lane).
template <bool F16>
__global__ __launch_bounds__(256) void roialign_kernel(
    const float* __restrict__ p3, const float* __restrict__ p4,
    const _Float16* __restrict__ h3, const _Float16* __restrict__ h4p,
    const float* __restrict__ props, const int* __restrict__ order,
    float* __restrict__ out, int N, int BN)
{
    // bijective chunked XCD swizzle: XCD k gets contiguous sorted slots
    const int s   = blockIdx.x;
    const int q   = BN >> 3, rr = BN & 7;
    const int xcd = s & 7, idx = s >> 3;
    const int s2  = (xcd < rr ? xcd * (q + 1) : rr * (q + 1) + (xcd - rr) * q) + idx;
    const int roi = order[s2];
    const int b   = roi >= N ? 1 : 0;

    const f4 pv = ld4f(props + (size_t)roi * 4);
    const float y1 = pv.x, x1 = pv.y, y2 = pv.z, x2 = pv.w;
    const float dy = y2 - y1, dx = x2 - x1;

    const int lvl = roi_level(dy, dx);   // always 3 or 4 for this data
    const int H = lvl == 3 ? 128 : 64;
    const int W = H;
    const float hm1 = (float)(H - 1);

    const float*    fb = (lvl == 3 ? p3 : p4) + (size_t)b * H * W * 256;
    const _Float16* hb = (lvl == 3 ? h3 : h4p) + (size_t)b * H * W * 256;

    const int tid = threadIdx.x;
    const int pl  = tid >> 6;             // point lane 0..3
    const int cg  = (tid & 63) << 2;      // channel offset (x4)

    const int obase = roi * NPTS * 256 + cg;

    auto lodd = [&](int off) -> f4 {
        if (F16) {
            const h4 v = *(const h4*)(hb + off);
            f4 r; r.x = (float)v.x; r.y = (float)v.y;
            r.z = (float)v.z; r.w = (float)v.w;
            return r;
        }
        return ld4f(fb + off);
    };

    auto calc = [&](int p, int& o00, int& o01, int& o10, int& o11,
                    float& fx, float& fy) {
        const int py = p / POOL;
        const int px = p - py * POOL;
        const float ys = (y1 + (float)py * (1.0f / (POOL - 1)) * dy) * hm1;
        const float xs = (x1 + (float)px * (1.0f / (POOL - 1)) * dx) * hm1;
        const float y0f = floorf(ys);
        const float x0f = floorf(xs);
        fy = ys - y0f;
        fx = xs - x0f;
        int yA = (int)y0f; yA = yA < 0 ? 0 : (yA > H - 1 ? H - 1 : yA);
        int yB = yA + 1;   yB = yB > H - 1 ? H - 1 : yB;
        int xA = (int)x0f; xA = xA < 0 ? 0 : (xA > W - 1 ? W - 1 : xA);
        int xB = xA + 1;   xB = xB > W - 1 ? W - 1 : xB;
        const int rA = yA * W, rB = yB * W;
        o00 = (rA + xA) * 256 + cg;
        o01 = (rA + xB) * 256 + cg;
        o10 = (rB + xA) * 256 + cg;
        o11 = (rB + xB) * 256 + cg;
    };

    #pragma unroll
    for (int p0 = 0; p0 < 48; p0 += 8) {
        const int pa = p0 + pl;   // <= 43
        const int pb = pa + 4;    // <= 47
        int a00, a01, a10, a11, b00, b01, b10, b11;
        float afx, afy, bfx, bfy;
        calc(pa, a00, a01, a10, a11, afx, afy);
        calc(pb, b00, b01, b10, b11, bfx, bfy);

        const f4 va00 = lodd(a00), va01 = lodd(a01);
        const f4 va10 = lodd(a10), va11 = lodd(a11);
        const f4 vb00 = lodd(b00), vb01 = lodd(b01);
        const f4 vb10 = lodd(b10), vb11 = lodd(b11);

        const f4 ta = va00 + afx * (va01 - va00);
        const f4 ba = va10 + afx * (va11 - va10);
        const f4 oa = ta + afy * (ba - ta);
        const f4 tb = vb00 + bfx * (vb01 - vb00);
        const f4 bb = vb10 + bfx * (vb11 - vb10);
        const f4 ob = tb + bfy * (bb - tb);

        __builtin_nontemporal_store(oa, (f4*)(out + obase + pa * 256));
        __builtin_nontemporal_store(ob, (f4*)(out + obase + pb * 256));
    }

    if (pl == 0) {  // tail: point 48
        int o00, o01, o10, o11;
        float fx, fy;
        calc(48, o00, o01, o10, o11, fx, fy);
        const f4 v00 = lodd(o00), v01 = lodd(o01);
        const f4 v10 = lodd(o10), v11 = lodd(o11);
        const f4 t  = v00 + fx * (v01 - v00);
        const f4 bo = v10 + fx * (v11 - v10);
        const f4 o  = t + fy * (bo - t);
        __builtin_nontemporal_store(o, (f4*)(out + obase + 48 * 256));
    }
}

extern "C" void kernel_launch(void* const* d_in, const int* in_sizes, int n_in,
                              void* d_out, int out_size, void* d_ws, size_t ws_size,
                              hipStream_t stream) {
    (void)n_in; (void)out_size;

    const float* p3 = (const float*)d_in[0];
    const float* p4 = (const float*)d_in[1];
    const float* props = (const float*)d_in[4];
    float* out = (float*)d_out;

    const int B = 2;
    const int N = in_sizes[4] / (B * 4);          // 1000
    const int BN = B * N;

    const int n3 = in_sizes[0];                   // 8388608 floats
    const int n4 = in_sizes[1];                   // 2097152 floats
    const int ntot = n3 + n4;

    int* order = (int*)d_ws;
    _Float16* hmem = (_Float16*)((char*)d_ws + 8192);
    const size_t need = 8192 + (size_t)ntot * sizeof(_Float16);

    if (ws_size >= need) {
        prepass_kernel<<<NB_CONV + 1, 256, 0, stream>>>(
            p3, (const float*)d_in[1], hmem, n3 / 4, ntot / 4,
            props, order, BN, N);
        roialign_kernel<true><<<BN, 256, 0, stream>>>(
            p3, (const float*)d_in[1], hmem, hmem + n3,
            props, order, out, N, BN);
    } else {
        // fallback: sort-only prepass (convert blocks see ntot_4 = 0)
        prepass_kernel<<<NB_CONV + 1, 256, 0, stream>>>(
            p3, (const float*)d_in[1], (_Float16*)d_ws, 0, 0,
            props, order, BN, N);
        roialign_kernel<false><<<BN, 256, 0, stream>>>(
            p3, (const float*)d_in[1], nullptr, nullptr,
            props, order, out, N, BN);
    }
}

// Round 6
// 35.742 us; speedup vs baseline: 1.1761x; 1.1761x over previous
//
#include <hip/hip_runtime.h>

#define POOL 7
#define NPTS 49

typedef float f4 __attribute__((ext_vector_type(4)));

__device__ __forceinline__ f4 ld4(const float* p) { return *(const f4*)p; }

__device__ __forceinline__ int roi_level(float dy, float dx) {
    // matches jnp: log2(sqrt(max(h*w,0)) / 0.21875 + 1e-8), round half-even
    const float rl = log2f(sqrtf(fmaxf(dy * dx, 0.0f)) / 0.21875f + 1e-8f);
    int lvl = 4 + (int)rintf(rl);
    return lvl < 3 ? 3 : (lvl > 6 ? 6 : lvl);
}

__device__ __forceinline__ int bucket_key(const float* props, int r, int N) {
    const f4 p = ld4(props + (size_t)r * 4);
    const int lvl = roi_level(p.z - p.x, p.w - p.y);
    const float yc = 0.5f * (p.x + p.z);
    int oct = (int)(yc * 8.0f);
    oct = oct < 0 ? 0 : (oct > 7 ? 7 : oct);
    int lg = lvl - 3; lg = lg < 0 ? 0 : (lg > 1 ? 1 : lg);  // data only hits {3,4}
    const int b = r >= N ? 1 : 0;
    return ((b << 1) | lg) * 8 + oct;   // [0,32)
}

// Single-block counting sort: order[] gets ROI indices grouped by
// (batch, level, y-octant) -> spatially/level coherent chunks. (round-3 proven)
__global__ __launch_bounds__(1024) void bucket_kernel(
    const float* __restrict__ props, int* __restrict__ order, int BN, int N)
{
    __shared__ int hist[32];
    __shared__ int offs[32];
    const int tid = threadIdx.x;
    if (tid < 32) hist[tid] = 0;
    __syncthreads();
    for (int r = tid; r < BN; r += 1024)
        atomicAdd(&hist[bucket_key(props, r, N)], 1);
    __syncthreads();
    if (tid == 0) {
        int acc = 0;
        for (int i = 0; i < 32; ++i) { offs[i] = acc; acc += hist[i]; }
    }
    __syncthreads();
    for (int r = tid; r < BN; r += 1024) {
        const int k = bucket_key(props, r, N);
        const int pos = atomicAdd(&offs[k], 1);
        order[pos] = r;
    }
}

// One block per sorted ROI slot. Two sequential channel phases (128 ch each)
// halve the instantaneous per-XCD read footprint -> L2-resident.
// Per phase: 256 threads = 8 point-lanes x 32 channel-lanes (float4).
__global__ __launch_bounds__(256) void roialign_kernel(
    const float* __restrict__ p3, const float* __restrict__ p4,
    const float* __restrict__ p5, const float* __restrict__ p6,
    const float* __restrict__ props, const int* __restrict__ order,
    float* __restrict__ out, int B, int N, int C, int nwg)
{
    // bijective chunked XCD swizzle (m204)
    const int s   = blockIdx.x;
    const int q   = nwg >> 3, rr = nwg & 7;
    const int xcd = s & 7, idx = s >> 3;
    const int s2  = (xcd < rr ? xcd * (q + 1) : rr * (q + 1) + (xcd - rr) * q) + idx;
    const int roi = order[s2];
    const int b   = roi >= N ? 1 : 0;

    const f4 pv = ld4(props + (size_t)roi * 4);
    const float y1 = pv.x, x1 = pv.y, y2 = pv.z, x2 = pv.w;
    const float dy = y2 - y1, dx = x2 - x1;

    const int lvl = roi_level(dy, dx);
    const float* f;
    int H;
    if      (lvl == 3) { f = p3; H = 128; }
    else if (lvl == 4) { f = p4; H = 64;  }
    else if (lvl == 5) { f = p5; H = 32;  }
    else               { f = p6; H = 16;  }
    const int W = H;
    const float hm1 = (float)(H - 1);
    const float* fb = f + (size_t)b * H * W * C;

    const int tid = threadIdx.x;
    const int pl  = tid >> 5;             // point lane 0..7
    const int clo = (tid & 31) << 2;      // channel offset within phase (float4)

    for (int phase = 0; phase < 2; ++phase) {
        const int cg = (phase << 7) + clo;       // 0..127 | 128..255
        const int obase = roi * NPTS * C + cg;

        auto calc = [&](int p, int& o00, int& o01, int& o10, int& o11,
                        float& fx, float& fy) {
            const int py = p / POOL;
            const int px = p - py * POOL;
            const float ys = (y1 + (float)py * (1.0f / (POOL - 1)) * dy) * hm1;
            const float xs = (x1 + (float)px * (1.0f / (POOL - 1)) * dx) * hm1;
            const float y0f = floorf(ys);
            const float x0f = floorf(xs);
            fy = ys - y0f;
            fx = xs - x0f;
            int yA = (int)y0f; yA = yA < 0 ? 0 : (yA > H - 1 ? H - 1 : yA);
            int yB = yA + 1;   yB = yB > H - 1 ? H - 1 : yB;
            int xA = (int)x0f; xA = xA < 0 ? 0 : (xA > W - 1 ? W - 1 : xA);
            int xB = xA + 1;   xB = xB > W - 1 ? W - 1 : xB;
            const int rA = yA * W, rB = yB * W;
            o00 = (rA + xA) * C + cg;
            o01 = (rA + xB) * C + cg;
            o10 = (rB + xA) * C + cg;
            o11 = (rB + xB) * C + cg;
        };

        #pragma unroll
        for (int p0 = 0; p0 < 48; p0 += 16) {
            const int pa = p0 + pl;   // <= 39
            const int pb = pa + 8;    // <= 47
            int a00, a01, a10, a11, b00, b01, b10, b11;
            float afx, afy, bfx, bfy;
            calc(pa, a00, a01, a10, a11, afx, afy);
            calc(pb, b00, b01, b10, b11, bfx, bfy);

            const f4 va00 = ld4(fb + a00), va01 = ld4(fb + a01);
            const f4 va10 = ld4(fb + a10), va11 = ld4(fb + a11);
            const f4 vb00 = ld4(fb + b00), vb01 = ld4(fb + b01);
            const f4 vb10 = ld4(fb + b10), vb11 = ld4(fb + b11);

            const f4 ta = va00 + afx * (va01 - va00);
            const f4 ba = va10 + afx * (va11 - va10);
            const f4 oa = ta + afy * (ba - ta);
            const f4 tb = vb00 + bfx * (vb01 - vb00);
            const f4 bb = vb10 + bfx * (vb11 - vb10);
            const f4 ob = tb + bfy * (bb - tb);

            __builtin_nontemporal_store(oa, (f4*)(out + obase + pa * C));
            __builtin_nontemporal_store(ob, (f4*)(out + obase + pb * C));
        }

        if (pl == 0) {  // tail: point 48 (32 threads cover this phase's 128 ch)
            int o00, o01, o10, o11;
            float fx, fy;
            calc(48, o00, o01, o10, o11, fx, fy);
            const f4 v00 = ld4(fb + o00), v01 = ld4(fb + o01);
            const f4 v10 = ld4(fb + o10), v11 = ld4(fb + o11);
            const f4 t  = v00 + fx * (v01 - v00);
            const f4 bo = v10 + fx * (v11 - v10);
            const f4 o  = t + fy * (bo - t);
            __builtin_nontemporal_store(o, (f4*)(out + obase + 48 * C));
        }
    }
}

extern "C" void kernel_launch(void* const* d_in, const int* in_sizes, int n_in,
                              void* d_out, int out_size, void* d_ws, size_t ws_size,
                              hipStream_t stream) {
    (void)ws_size; (void)n_in; (void)out_size;

    const float* p3 = (const float*)d_in[0];
    const float* p4 = (const float*)d_in[1];
    const float* p5 = (const float*)d_in[2];
    const float* p6 = (const float*)d_in[3];
    const float* props = (const float*)d_in[4];
    float* out = (float*)d_out;
    int* order = (int*)d_ws;

    const int B = 2;
    const int N = in_sizes[4] / (B * 4);          // 1000
    const int C = in_sizes[0] / (B * 128 * 128);  // 256
    const int BN = B * N;

    bucket_kernel<<<1, 1024, 0, stream>>>(props, order, BN, N);
    roialign_kernel<<<BN, 256, 0, stream>>>(p3, p4, p5, p6, props, order,
                                            out, B, N, C, BN);
}

// Round 7
// 32.844 us; speedup vs baseline: 1.2798x; 1.0882x over previous
//
#include <hip/hip_runtime.h>

#define POOL 7
#define NPTS 49

typedef float f4 __attribute__((ext_vector_type(4)));

__device__ __forceinline__ f4 ld4(const float* p) { return *(const f4*)p; }

__device__ __forceinline__ int roi_level(float dy, float dx) {
    // matches jnp: log2(sqrt(max(h*w,0)) / 0.21875 + 1e-8), round half-even
    const float rl = log2f(sqrtf(fmaxf(dy * dx, 0.0f)) / 0.21875f + 1e-8f);
    int lvl = 4 + (int)rintf(rl);
    return lvl < 3 ? 3 : (lvl > 6 ? 6 : lvl);
}

__device__ __forceinline__ int bucket_key(const float* props, int r, int N) {
    const f4 p = ld4(props + (size_t)r * 4);
    const int lvl = roi_level(p.z - p.x, p.w - p.y);
    const float yc = 0.5f * (p.x + p.z);
    int oct = (int)(yc * 8.0f);
    oct = oct < 0 ? 0 : (oct > 7 ? 7 : oct);
    int lg = lvl - 3; lg = lg < 0 ? 0 : (lg > 1 ? 1 : lg);  // data only hits {3,4}
    const int b = r >= N ? 1 : 0;
    return ((b << 1) | lg) * 8 + oct;   // [0,32)
}

// Single-block counting sort: order[] gets ROI indices grouped by
// (batch, level, y-octant) -> spatially/level coherent chunks. (round-3 proven)
__global__ __launch_bounds__(1024) void bucket_kernel(
    const float* __restrict__ props, int* __restrict__ order, int BN, int N)
{
    __shared__ int hist[32];
    __shared__ int offs[32];
    const int tid = threadIdx.x;
    if (tid < 32) hist[tid] = 0;
    __syncthreads();
    for (int r = tid; r < BN; r += 1024)
        atomicAdd(&hist[bucket_key(props, r, N)], 1);
    __syncthreads();
    if (tid == 0) {
        int acc = 0;
        for (int i = 0; i < 32; ++i) { offs[i] = acc; acc += hist[i]; }
    }
    __syncthreads();
    for (int r = tid; r < BN; r += 1024) {
        const int k = bucket_key(props, r, N);
        const int pos = atomicAdd(&offs[k], 1);
        order[pos] = r;
    }
}

// One block per sorted ROI slot. 256 threads = 4 point-lanes x 64 channel-lanes.
// Stores are software-pipelined one iteration behind the loads so the
// compiler can wait vmcnt(2) for load data while NT stores stay in flight.
__global__ __launch_bounds__(256) void roialign_kernel(
    const float* __restrict__ p3, const float* __restrict__ p4,
    const float* __restrict__ p5, const float* __restrict__ p6,
    const float* __restrict__ props, const int* __restrict__ order,
    float* __restrict__ out, int B, int N, int C, int nwg)
{
    // bijective chunked XCD swizzle (m204)
    const int s   = blockIdx.x;
    const int q   = nwg >> 3, rr = nwg & 7;
    const int xcd = s & 7, idx = s >> 3;
    const int s2  = (xcd < rr ? xcd * (q + 1) : rr * (q + 1) + (xcd - rr) * q) + idx;
    const int roi = order[s2];
    const int b   = roi >= N ? 1 : 0;

    const f4 pv = ld4(props + (size_t)roi * 4);
    const float y1 = pv.x, x1 = pv.y, y2 = pv.z, x2 = pv.w;
    const float dy = y2 - y1, dx = x2 - x1;

    const int lvl = roi_level(dy, dx);
    const float* f;
    int H;
    if      (lvl == 3) { f = p3; H = 128; }
    else if (lvl == 4) { f = p4; H = 64;  }
    else if (lvl == 5) { f = p5; H = 32;  }
    else               { f = p6; H = 16;  }
    const int W = H;
    const float hm1 = (float)(H - 1);
    const float* fb = f + (size_t)b * H * W * C;

    const int tid = threadIdx.x;
    const int pl  = tid >> 6;             // point lane 0..3
    const int cg  = (tid & 63) << 2;      // channel offset (float4)

    const int obase = roi * NPTS * C + cg;

    auto calc = [&](int p, int& o00, int& o01, int& o10, int& o11,
                    float& fx, float& fy) {
        const int py = p / POOL;
        const int px = p - py * POOL;
        const float ys = (y1 + (float)py * (1.0f / (POOL - 1)) * dy) * hm1;
        const float xs = (x1 + (float)px * (1.0f / (POOL - 1)) * dx) * hm1;
        const float y0f = floorf(ys);
        const float x0f = floorf(xs);
        fy = ys - y0f;
        fx = xs - x0f;
        int yA = (int)y0f; yA = yA < 0 ? 0 : (yA > H - 1 ? H - 1 : yA);
        int yB = yA + 1;   yB = yB > H - 1 ? H - 1 : yB;
        int xA = (int)x0f; xA = xA < 0 ? 0 : (xA > W - 1 ? W - 1 : xA);
        int xB = xA + 1;   xB = xB > W - 1 ? W - 1 : xB;
        const int rA = yA * W, rB = yB * W;
        o00 = (rA + xA) * C + cg;
        o01 = (rA + xB) * C + cg;
        o10 = (rB + xA) * C + cg;
        o11 = (rB + xB) * C + cg;
    };

    f4 oa_p, ob_p;            // deferred (previous iteration) results
    int pa_p = -1, pb_p = -1;

    #pragma unroll
    for (int p0 = 0; p0 < 48; p0 += 8) {
        const int pa = p0 + pl;   // <= 43
        const int pb = pa + 4;    // <= 47
        int a00, a01, a10, a11, b00, b01, b10, b11;
        float afx, afy, bfx, bfy;
        calc(pa, a00, a01, a10, a11, afx, afy);
        calc(pb, b00, b01, b10, b11, bfx, bfy);

        // issue this iteration's 8 loads FIRST ...
        const f4 va00 = ld4(fb + a00), va01 = ld4(fb + a01);
        const f4 va10 = ld4(fb + a10), va11 = ld4(fb + a11);
        const f4 vb00 = ld4(fb + b00), vb01 = ld4(fb + b01);
        const f4 vb10 = ld4(fb + b10), vb11 = ld4(fb + b11);

        // ... then retire the PREVIOUS iteration's stores (folds away at p0==0)
        if (pa_p >= 0) {
            __builtin_nontemporal_store(oa_p, (f4*)(out + obase + pa_p * C));
            __builtin_nontemporal_store(ob_p, (f4*)(out + obase + pb_p * C));
        }

        const f4 ta = va00 + afx * (va01 - va00);
        const f4 ba = va10 + afx * (va11 - va10);
        const f4 oa = ta + afy * (ba - ta);
        const f4 tb = vb00 + bfx * (vb01 - vb00);
        const f4 bb = vb10 + bfx * (vb11 - vb10);
        const f4 ob = tb + bfy * (bb - tb);

        oa_p = oa; ob_p = ob; pa_p = pa; pb_p = pb;
    }

    // tail: point 48 loads first, then the last deferred pair, then finish
    if (pl == 0) {
        int o00, o01, o10, o11;
        float fx, fy;
        calc(48, o00, o01, o10, o11, fx, fy);
        const f4 v00 = ld4(fb + o00), v01 = ld4(fb + o01);
        const f4 v10 = ld4(fb + o10), v11 = ld4(fb + o11);

        __builtin_nontemporal_store(oa_p, (f4*)(out + obase + pa_p * C));
        __builtin_nontemporal_store(ob_p, (f4*)(out + obase + pb_p * C));

        const f4 t  = v00 + fx * (v01 - v00);
        const f4 bo = v10 + fx * (v11 - v10);
        const f4 o  = t + fy * (bo - t);
        __builtin_nontemporal_store(o, (f4*)(out + obase + 48 * C));
    } else {
        __builtin_nontemporal_store(oa_p, (f4*)(out + obase + pa_p * C));
        __builtin_nontemporal_store(ob_p, (f4*)(out + obase + pb_p * C));
    }
}

extern "C" void kernel_launch(void* const* d_in, const int* in_sizes, int n_in,
                              void* d_out, int out_size, void* d_ws, size_t ws_size,
                              hipStream_t stream) {
    (void)ws_size; (void)n_in; (void)out_size;

    const float* p3 = (const float*)d_in[0];
    const float* p4 = (const float*)d_in[1];
    const float* p5 = (const float*)d_in[2];
    const float* p6 = (const float*)d_in[3];
    const float* props = (const float*)d_in[4];
    float* out = (float*)d_out;
    int* order = (int*)d_ws;

    const int B = 2;
    const int N = in_sizes[4] / (B * 4);          // 1000
    const int C = in_sizes[0] / (B * 128 * 128);  // 256
    const int BN = B * N;

    bucket_kernel<<<1, 1024, 0, stream>>>(props, order, BN, N);
    roialign_kernel<<<BN, 256, 0, stream>>>(p3, p4, p5, p6, props, order,
                                            out, B, N, C, BN);
}